// Round 11
// baseline (393.338 us; speedup 1.0000x reference)
//
#include <hip/hip_runtime.h>
#include <math.h>

// WaveletKANClassifier, MI355X gfx950. fp32 I/O, bf16 MFMA compute.
//
// Round-15: single-dispatch via atomic grid barrier (NOT cooperative —
// R7 showed coop launch costs ~157us in this harness's graph replay).
// Evidence: fused K-loop is pinned at ~131-133us across 6 structural
// nulls (load mech, fences, occupancy, tile, traffic, barrier freq);
// meanwhile total-minus-kernels ≈ 60-65us PER DISPATCH NODE (R0→R1:
// +1 kernel = +67us; R0/R5/R6 consistent). So: eliminate the pack node.
//  - grid 256 = exactly 1 block/CU at our ~240-reg/wave footprint
//    (128 arch VGPR + 112 AGPR, unified file) -> all blocks co-resident
//    by capacity arithmetic -> atomic spin barrier is deadlock-free
//    with a plain launch.
//  - in-kernel pack phase (R7-validated), __threadfence release/acquire
//    around the barrier; pack is idempotent so replay staleness benign.
//  - barrier counter zeroed by 4-byte hipMemsetAsync (graph-capturable).
//  - 2 passes of R10's exact superstep body (131.6us best).

#define B_SZ  32768
#define DIN   768
#define DOUT  768
#define NWAV  48

// d_ws fragment-major layout (units: shorts). Fragment tile = 64 lanes x 8
// bf16 = 512 shorts; lane L holds M[c0+(L&31)][k0 + (L>>5)*8 + j].
#define WF_OFF   0        // W:  24 cb x 48 kb tiles = 589824
#define WPH_OFF  589824   // Wp hi: 2 ct x 48 kb = 49152
#define WPL_OFF  638976   // Wp lo: 49152
#define WCF_OFF  688128   // Wc: 24 cb x 3 kb = 36864
#define CTR_OFF  724992   // u32 grid-barrier counter (memset to 0 per launch)

typedef short bf16x8 __attribute__((ext_vector_type(8)));
typedef float f32x16 __attribute__((ext_vector_type(16)));

__device__ __forceinline__ float bf2f(short u) {
    union { unsigned int i; float f; } v;
    v.i = ((unsigned int)(unsigned short)u) << 16;
    return v.f;
}
__device__ __forceinline__ short f2bf(float f) {
    union { float f; unsigned int i; } v; v.f = f;
    unsigned int r = v.i + 0x7FFFu + ((v.i >> 16) & 1u);  // RNE
    return (short)(r >> 16);
}

// ---------------------------------------------------------------- fused
// grid 256 x 512. Phase 0: pack weights (blocks 0..164, 8 tiles each).
// Atomic grid barrier. Then 2 passes x (64 rows x 768 cols), 8 waves.
__global__ __launch_bounds__(512, 2) void fused_kernel(
    const float* __restrict__ x,  const float* __restrict__ W,
    const float* __restrict__ Wp, const float* __restrict__ Wc,
    short* __restrict__ ws,
    const float* __restrict__ bp, const float* __restrict__ sc,
    const float* __restrict__ tr,
    const float* __restrict__ bb, const float* __restrict__ bc,
    const float* __restrict__ gm, const float* __restrict__ bt,
    float* __restrict__ out)
{
    // x tiles: 64 rows x 64 k bf16, row stride 72 shorts. FOUR buffers
    // (rotation k&3), hi + lo. One barrier per 2-chunk superstep.
    __shared__ __align__(16) short xh[4][64 * 72];
    __shared__ __align__(16) short xl[4][64 * 72];
    __shared__ float redS[64 * 8], redQ[64 * 8];
    __shared__ float muA[64], rsA[64];
    __shared__ unsigned flags[64];      // bit j: (row, haar j) boundary band
    __shared__ double dred[8];

    const int tid = threadIdx.x;
    const int L   = tid & 63;
    const int wv  = __builtin_amdgcn_readfirstlane(tid >> 6);  // wave-uniform
    const int lm  = L & 31, half = L >> 5;
    const int L8  = L * 8;
    const bool wi = (wv < 4);      // waves 0-3 also compute wi = x@Wp^T
    const int wv3 = wv * 3;
    const int wrt = wv & 1, wct = wv >> 1;     // wi tile for wv<4
    const int wct48 = wct * 48;

    // ---------------- phase 0: pack weights into ws (1320 fragment tiles)
    {
        const int gw = blockIdx.x * 8 + wv;
        if (gw < 1152) {                       // W [768 x 768]
            const int cb = gw / 48, kb = gw % 48;
            const int row = cb * 32 + lm;
            const int k = kb * 16 + half * 8;
            bf16x8 o;
#pragma unroll
            for (int j = 0; j < 8; j++) o[j] = f2bf(W[(size_t)row * DIN + k + j]);
            *reinterpret_cast<bf16x8*>(&ws[WF_OFF + (size_t)gw * 512 + L8]) = o;
        } else if (gw < 1248) {                // Wp [48 x 768], hi/lo, pad->64
            const int t = gw - 1152;
            const int ct = t / 48, kb = t % 48;
            const int j = ct * 32 + lm;
            const int k = kb * 16 + half * 8;
            bf16x8 h, l;
#pragma unroll
            for (int jj = 0; jj < 8; jj++) {
                float v = (j < NWAV) ? Wp[(size_t)j * DIN + k + jj] : 0.f;
                const short hh = f2bf(v);
                h[jj] = hh;
                l[jj] = f2bf(v - bf2f(hh));
            }
            *reinterpret_cast<bf16x8*>(&ws[WPH_OFF + (size_t)t * 512 + L8]) = h;
            *reinterpret_cast<bf16x8*>(&ws[WPL_OFF + (size_t)t * 512 + L8]) = l;
        } else if (gw < 1320) {                // Wc [768 x 48]
            const int t = gw - 1248;
            const int cb = t / 3, kb = t % 3;
            const int row = cb * 32 + lm;
            const int k = kb * 16 + half * 8;
            bf16x8 o;
#pragma unroll
            for (int jj = 0; jj < 8; jj++) o[jj] = f2bf(Wc[(size_t)row * NWAV + k + jj]);
            *reinterpret_cast<bf16x8*>(&ws[WCF_OFF + (size_t)t * 512 + L8]) = o;
        }
    }

    // ---------------- atomic grid barrier (all 256 blocks co-resident:
    // grid == CU count, 1 block/CU capacity -> deadlock-free w/o coop).
    {
        unsigned* ctr = reinterpret_cast<unsigned*>(ws + CTR_OFF);
        __syncthreads();                       // block's pack stores done
        if (tid == 0) {
            __threadfence();                   // release pack stores
            atomicAdd(ctr, 1u);
            while (atomicAdd(ctr, 0u) < 256u) { }   // device-scope spin
            __threadfence();                   // acquire
        }
        __syncthreads();
    }

    const short* WF  = ws + WF_OFF;
    const short* WPH = ws + WPH_OFF;
    const short* WPL = ws + WPL_OFF;
    const short* WCF = ws + WCF_OFF;

    // staging role: thread -> (row, 8-k chunk); 8 threads per row
    const int srow = tid >> 3;
    const int sk   = (tid & 7) * 8;

#pragma unroll 1
    for (int pass = 0; pass < 2; ++pass) {
        const int r0 = (blockIdx.x + (pass << 8)) * 64;

        if (tid < 64) flags[tid] = 0u;

        f32x16 acc[2][3];          // [rt (row 32-block)][ct (col 32-block)]
#pragma unroll
        for (int rt = 0; rt < 2; rt++)
#pragma unroll
            for (int ct = 0; ct < 3; ct++)
#pragma unroll
                for (int g = 0; g < 16; g++) acc[rt][ct][g] = 0.f;
        f32x16 wacc;               // wi acc (waves 0-3)
#pragma unroll
        for (int g = 0; g < 16; g++) wacc[g] = 0.f;

        // ---- prologue: stage x chunks 0,1 into buffers 0,1
#pragma unroll
        for (int c = 0; c < 2; ++c) {
            const float4* xp = reinterpret_cast<const float4*>(
                &x[(size_t)(r0 + srow) * DIN + c * 64 + sk]);
            const float4 v0 = xp[0], v1 = xp[1];
            const float f[8] = {v0.x, v0.y, v0.z, v0.w, v1.x, v1.y, v1.z, v1.w};
            bf16x8 hh, ll;
#pragma unroll
            for (int i = 0; i < 8; i++) {
                const short h = f2bf(f[i]);
                hh[i] = h;
                ll[i] = f2bf(f[i] - bf2f(h));
            }
            *reinterpret_cast<bf16x8*>(&xh[c][srow * 72 + sk]) = hh;
            *reinterpret_cast<bf16x8*>(&xl[c][srow * 72 + sk]) = ll;
        }
        __syncthreads();

        // ---- K loop: 6 supersteps of 2 chunks
        for (int s = 0; s < 6; ++s) {
            const int kA = 2 * s, kB = 2 * s + 1;
            const int bA = kA & 3, bB = kB & 3;
            const int kbA = kA * 4, kbB = kB * 4;

            // ---- chunk A: weight loads
            bf16x8 bfrA[4][3];
#pragma unroll
            for (int ks = 0; ks < 4; ++ks)
#pragma unroll
                for (int ct = 0; ct < 3; ++ct)
                    bfrA[ks][ct] = *reinterpret_cast<const bf16x8*>(
                        &WF[((size_t)((wv3 + ct) * 48 + kbA + ks)) * 512 + L8]);
            bf16x8 bwhA[4], bwlA[4];
            if (wi) {
#pragma unroll
                for (int ks = 0; ks < 4; ++ks) {
                    bwhA[ks] = *reinterpret_cast<const bf16x8*>(
                        &WPH[((size_t)(wct48 + kbA + ks)) * 512 + L8]);
                    bwlA[ks] = *reinterpret_cast<const bf16x8*>(
                        &WPL[((size_t)(wct48 + kbA + ks)) * 512 + L8]);
                }
            }
            float4 vA0, vA1;
            if (s < 5) {
                const float4* xp = reinterpret_cast<const float4*>(
                    &x[(size_t)(r0 + srow) * DIN + (kA + 2) * 64 + sk]);
                vA0 = xp[0]; vA1 = xp[1];
            }

            // ---- chunk A: MFMA
#pragma unroll
            for (int ks = 0; ks < 4; ++ks) {
                const bf16x8 a0 = *reinterpret_cast<bf16x8*>(
                    &xh[bA][lm * 72 + ks * 16 + half * 8]);
                const bf16x8 a1 = *reinterpret_cast<bf16x8*>(
                    &xh[bA][(32 + lm) * 72 + ks * 16 + half * 8]);
#pragma unroll
                for (int ct = 0; ct < 3; ++ct) {
                    acc[0][ct] = __builtin_amdgcn_mfma_f32_32x32x16_bf16(a0, bfrA[ks][ct], acc[0][ct], 0, 0, 0);
                    acc[1][ct] = __builtin_amdgcn_mfma_f32_32x32x16_bf16(a1, bfrA[ks][ct], acc[1][ct], 0, 0, 0);
                }
                if (wi) {
                    const bf16x8 ah = wrt ? a1 : a0;
                    const bf16x8 al = *reinterpret_cast<bf16x8*>(
                        &xl[bA][(wrt * 32 + lm) * 72 + ks * 16 + half * 8]);
                    wacc = __builtin_amdgcn_mfma_f32_32x32x16_bf16(ah, bwlA[ks], wacc, 0, 0, 0);
                    wacc = __builtin_amdgcn_mfma_f32_32x32x16_bf16(al, bwhA[ks], wacc, 0, 0, 0);
                    wacc = __builtin_amdgcn_mfma_f32_32x32x16_bf16(ah, bwhA[ks], wacc, 0, 0, 0);
                }
            }

            // ---- chunk B: weight loads (no fence: may issue under MFMA A)
            bf16x8 bfrB[4][3];
#pragma unroll
            for (int ks = 0; ks < 4; ++ks)
#pragma unroll
                for (int ct = 0; ct < 3; ++ct)
                    bfrB[ks][ct] = *reinterpret_cast<const bf16x8*>(
                        &WF[((size_t)((wv3 + ct) * 48 + kbB + ks)) * 512 + L8]);
            bf16x8 bwhB[4], bwlB[4];
            if (wi) {
#pragma unroll
                for (int ks = 0; ks < 4; ++ks) {
                    bwhB[ks] = *reinterpret_cast<const bf16x8*>(
                        &WPH[((size_t)(wct48 + kbB + ks)) * 512 + L8]);
                    bwlB[ks] = *reinterpret_cast<const bf16x8*>(
                        &WPL[((size_t)(wct48 + kbB + ks)) * 512 + L8]);
                }
            }
            float4 vB0, vB1;
            if (s < 5) {
                const float4* xp = reinterpret_cast<const float4*>(
                    &x[(size_t)(r0 + srow) * DIN + (kB + 2) * 64 + sk]);
                vB0 = xp[0]; vB1 = xp[1];
            }

            // ---- chunk B: MFMA
#pragma unroll
            for (int ks = 0; ks < 4; ++ks) {
                const bf16x8 a0 = *reinterpret_cast<bf16x8*>(
                    &xh[bB][lm * 72 + ks * 16 + half * 8]);
                const bf16x8 a1 = *reinterpret_cast<bf16x8*>(
                    &xh[bB][(32 + lm) * 72 + ks * 16 + half * 8]);
#pragma unroll
                for (int ct = 0; ct < 3; ++ct) {
                    acc[0][ct] = __builtin_amdgcn_mfma_f32_32x32x16_bf16(a0, bfrB[ks][ct], acc[0][ct], 0, 0, 0);
                    acc[1][ct] = __builtin_amdgcn_mfma_f32_32x32x16_bf16(a1, bfrB[ks][ct], acc[1][ct], 0, 0, 0);
                }
                if (wi) {
                    const bf16x8 ah = wrt ? a1 : a0;
                    const bf16x8 al = *reinterpret_cast<bf16x8*>(
                        &xl[bB][(wrt * 32 + lm) * 72 + ks * 16 + half * 8]);
                    wacc = __builtin_amdgcn_mfma_f32_32x32x16_bf16(ah, bwlB[ks], wacc, 0, 0, 0);
                    wacc = __builtin_amdgcn_mfma_f32_32x32x16_bf16(al, bwhB[ks], wacc, 0, 0, 0);
                    wacc = __builtin_amdgcn_mfma_f32_32x32x16_bf16(ah, bwhB[ks], wacc, 0, 0, 0);
                }
            }

            // ---- stage chunks kA+2, kB+2 into buffers (kA+2)&3, (kB+2)&3
            if (s < 5) {
                {
                    const float f[8] = {vA0.x, vA0.y, vA0.z, vA0.w, vA1.x, vA1.y, vA1.z, vA1.w};
                    bf16x8 hh, ll;
#pragma unroll
                    for (int i = 0; i < 8; i++) {
                        const short h = f2bf(f[i]);
                        hh[i] = h;
                        ll[i] = f2bf(f[i] - bf2f(h));
                    }
                    const int bn = (kA + 2) & 3;
                    *reinterpret_cast<bf16x8*>(&xh[bn][srow * 72 + sk]) = hh;
                    *reinterpret_cast<bf16x8*>(&xl[bn][srow * 72 + sk]) = ll;
                }
                {
                    const float f[8] = {vB0.x, vB0.y, vB0.z, vB0.w, vB1.x, vB1.y, vB1.z, vB1.w};
                    bf16x8 hh, ll;
#pragma unroll
                    for (int i = 0; i < 8; i++) {
                        const short h = f2bf(f[i]);
                        hh[i] = h;
                        ll[i] = f2bf(f[i] - bf2f(h));
                    }
                    const int bn = (kB + 2) & 3;
                    *reinterpret_cast<bf16x8*>(&xh[bn][srow * 72 + sk]) = hh;
                    *reinterpret_cast<bf16x8*>(&xl[bn][srow * 72 + sk]) = ll;
                }
            }
            __syncthreads();
        }

        // ---- wavelet activation + GELU -> wav tile in LDS (reuse xh[0])
        short* wavL = &xh[0][0];
        if (wi) {
            const int j = wct * 32 + lm;
            if (j < NWAV) {
                const float bpv = bp[j], scv = sc[j], trv = tr[j];
#pragma unroll
                for (int g = 0; g < 16; ++g) {
                    const int rowl = wrt * 32 + (g & 3) + 8 * (g >> 2) + 4 * half;  // C/D map
                    const float wiv = wacc[g] + bpv;
                    const float s = (wiv - trv) / scv;
                    float w;
                    if (j < 16) {
                        // haar: flag boundary band for the in-block recheck
                        const float dmin = fminf(fabsf(s), fminf(fabsf(s - 0.5f), fabsf(s - 1.0f)));
                        if (dmin < 2e-4f) atomicOr(&flags[rowl], 1u << j);
                        w = (s >= 0.f && s < 0.5f) ? 1.f : ((s >= 0.5f && s < 1.f) ? -1.f : 0.f);
                    } else if (j < 32) {
                        w = (1.f - s * s) * expf(-0.5f * s * s);
                    } else {
                        w = cosf(5.f * s) * expf(-0.5f * s * s);
                    }
                    const float gel = 0.5f * w * (1.f + erff(w * 0.70710678118654752f));
                    wavL[rowl * 72 + j] = f2bf(gel);
                }
            }
        }
        __syncthreads();

        // ---- block-parallel fp64 recheck of flagged (row, j) haar entries
#pragma unroll 1
        for (int fr = 0; fr < 64; ++fr) {
            unsigned m = flags[fr];
            while (m) {
                const int j = __ffs(m) - 1;
                m &= m - 1;
                const float* xr = &x[(size_t)(r0 + fr) * DIN];
                const float* wr = &Wp[(size_t)j * DIN];
                double a = (double)xr[tid] * (double)wr[tid];
                if (tid < DIN - 512)
                    a += (double)xr[tid + 512] * (double)wr[tid + 512];
                a += __shfl_xor(a, 1);  a += __shfl_xor(a, 2);
                a += __shfl_xor(a, 4);  a += __shfl_xor(a, 8);
                a += __shfl_xor(a, 16); a += __shfl_xor(a, 32);
                if (L == 0) dred[wv] = a;
                __syncthreads();
                if (tid == 0) {
                    double wid = (double)bp[j];
#pragma unroll
                    for (int i = 0; i < 8; i++) wid += dred[i];
                    const double sd = (wid - (double)tr[j]) / (double)sc[j];
                    const double w = (sd >= 0.0 && sd < 0.5) ? 1.0
                                   : ((sd >= 0.5 && sd < 1.0) ? -1.0 : 0.0);
                    const double gel = 0.5 * w * (1.0 + erf(w * 0.70710678118654752));
                    wavL[fr * 72 + j] = f2bf((float)gel);
                }
                __syncthreads();
            }
        }

        // ---- h += wav @ Wc^T  (K=48 -> 3 ksteps)
#pragma unroll
        for (int ks = 0; ks < 3; ++ks) {
            const bf16x8 a0 = *reinterpret_cast<bf16x8*>(&wavL[lm * 72 + ks * 16 + half * 8]);
            const bf16x8 a1 = *reinterpret_cast<bf16x8*>(&wavL[(32 + lm) * 72 + ks * 16 + half * 8]);
#pragma unroll
            for (int ct = 0; ct < 3; ++ct) {
                const bf16x8 b = *reinterpret_cast<const bf16x8*>(
                    &WCF[((size_t)((wv3 + ct) * 3 + ks)) * 512 + L8]);
                acc[0][ct] = __builtin_amdgcn_mfma_f32_32x32x16_bf16(a0, b, acc[0][ct], 0, 0, 0);
                acc[1][ct] = __builtin_amdgcn_mfma_f32_32x32x16_bf16(a1, b, acc[1][ct], 0, 0, 0);
            }
        }

        // ---- bias + LN reduction
        float bias[3], gmv[3], btv[3];
#pragma unroll
        for (int ct = 0; ct < 3; ++ct) {
            const int col = wv * 96 + ct * 32 + lm;
            bias[ct] = bb[col] + bc[col];
            gmv[ct] = gm[col];
            btv[ct] = bt[col];
        }
#pragma unroll
        for (int rt = 0; rt < 2; ++rt) {
#pragma unroll
            for (int g = 0; g < 16; ++g) {
                const float v0 = acc[rt][0][g] + bias[0];
                const float v1 = acc[rt][1][g] + bias[1];
                const float v2 = acc[rt][2][g] + bias[2];
                acc[rt][0][g] = v0; acc[rt][1][g] = v1; acc[rt][2][g] = v2;
                float s1 = v0 + v1 + v2;
                float s2 = v0 * v0 + v1 * v1 + v2 * v2;
                s1 += __shfl_xor(s1, 1);  s2 += __shfl_xor(s2, 1);
                s1 += __shfl_xor(s1, 2);  s2 += __shfl_xor(s2, 2);
                s1 += __shfl_xor(s1, 4);  s2 += __shfl_xor(s2, 4);
                s1 += __shfl_xor(s1, 8);  s2 += __shfl_xor(s2, 8);
                s1 += __shfl_xor(s1, 16); s2 += __shfl_xor(s2, 16);
                if (lm == 0) {
                    const int rowl = rt * 32 + (g & 3) + 8 * (g >> 2) + 4 * half;
                    redS[rowl * 8 + wv] = s1;
                    redQ[rowl * 8 + wv] = s2;
                }
            }
        }
        __syncthreads();
        if (tid < 64) {
            float S = 0.f, Q = 0.f;
#pragma unroll
            for (int i = 0; i < 8; i++) { S += redS[tid * 8 + i]; Q += redQ[tid * 8 + i]; }
            const float mu = S * (1.f / 768.f);
            const float var = Q * (1.f / 768.f) - mu * mu;
            muA[tid] = mu;
            rsA[tid] = rsqrtf(var + 1e-5f);
        }
        __syncthreads();

        // ---- normalize + store (f32)
#pragma unroll
        for (int rt = 0; rt < 2; ++rt) {
#pragma unroll
            for (int g = 0; g < 16; ++g) {
                const int rowl = rt * 32 + (g & 3) + 8 * (g >> 2) + 4 * half;
                const float mu = muA[rowl], rs = rsA[rowl];
                float* orow = &out[(size_t)(r0 + rowl) * DOUT + wv * 96 + lm];
#pragma unroll
                for (int ct = 0; ct < 3; ++ct) {
                    orow[ct * 32] = (acc[rt][ct][g] - mu) * rs * gmv[ct] + btv[ct];
                }
            }
        }
        // next pass's first write targets (flags / xh prologue) are only
        // read before this pass's post-LN barriers -> no extra barrier.
    }
}

// ---------------------------------------------------------------- launcher
extern "C" void kernel_launch(void* const* d_in, const int* in_sizes, int n_in,
                              void* d_out, int out_size, void* d_ws, size_t ws_size,
                              hipStream_t stream)
{
    const float* x  = (const float*)d_in[0];
    const float* W  = (const float*)d_in[1];
    const float* b  = (const float*)d_in[2];
    const float* Wp = (const float*)d_in[3];
    const float* bp = (const float*)d_in[4];
    const float* Wc = (const float*)d_in[5];
    const float* bc = (const float*)d_in[6];
    const float* sc = (const float*)d_in[7];
    const float* tr = (const float*)d_in[8];
    const float* gm = (const float*)d_in[9];
    const float* bt = (const float*)d_in[10];
    float* out = (float*)d_out;
    short* ws  = (short*)d_ws;   // ~1.45 MB packed weights + barrier ctr

    hipMemsetAsync(ws + CTR_OFF, 0, 4, stream);   // zero barrier counter
    fused_kernel<<<dim3(256), dim3(512), 0, stream>>>(
        x, W, Wp, Wc, ws, bp, sc, tr, b, bc, gm, bt, out);
}